// Round 11
// baseline (212.441 us; speedup 1.0000x reference)
//
#include <hip/hip_runtime.h>

// B=2, S=2048, D=1024, H=16, DH=64. fp32 in/out, f16 MFMA internally.
// ws: xb(8M) Wcat(6M)@8M Wot(2M)@14M Q(8M)@16M K(8M)@24M Vt(8M)@32M ctx(8M)@40M

typedef _Float16 f16;
typedef _Float16 f16x8 __attribute__((ext_vector_type(8)));
typedef _Float16 f16x4 __attribute__((ext_vector_type(4)));
typedef float    f32x4 __attribute__((ext_vector_type(4)));

__device__ __forceinline__ void gload16(const void* g, void* l) {
  __builtin_amdgcn_global_load_lds(
      (const __attribute__((address_space(1))) void*)g,
      (__attribute__((address_space(3))) void*)l, 16, 0, 0);
}

// ---------------- converts ----------------
__global__ void cvt_x(const float* __restrict__ x, f16* __restrict__ xb) {
  int idx = blockIdx.x * 256 + threadIdx.x;
  float4 v = ((const float4*)x)[idx];
  f16x4 o = { (f16)v.x, (f16)v.y, (f16)v.z, (f16)v.w };
  ((f16x4*)xb)[idx] = o;
}

__global__ void cvt_w(const float* __restrict__ W0, const float* __restrict__ W1,
                      const float* __restrict__ W2, const float* __restrict__ W3,
                      f16* __restrict__ T0, f16* __restrict__ T1,
                      f16* __restrict__ T2, f16* __restrict__ T3) {
  const float* W = blockIdx.z == 0 ? W0 : blockIdx.z == 1 ? W1 : blockIdx.z == 2 ? W2 : W3;
  f16*        Tt = blockIdx.z == 0 ? T0 : blockIdx.z == 1 ? T1 : blockIdx.z == 2 ? T2 : T3;
  __shared__ f16 tile[64][65];
  int tid = threadIdx.x;
  int k0 = blockIdx.y * 64, n0 = blockIdx.x * 64;
  int rr = tid >> 4, cc = (tid & 15) * 4;
#pragma unroll
  for (int p = 0; p < 4; ++p) {
    int r = rr + p * 16;
    float4 v = *(const float4*)(W + (size_t)(k0 + r) * 1024 + n0 + cc);
    tile[r][cc + 0] = (f16)v.x; tile[r][cc + 1] = (f16)v.y;
    tile[r][cc + 2] = (f16)v.z; tile[r][cc + 3] = (f16)v.w;
  }
  __syncthreads();
#pragma unroll
  for (int p = 0; p < 4; ++p) {
    int r = rr + p * 16;
    f16x4 v;
#pragma unroll
    for (int j = 0; j < 4; ++j) v[j] = tile[cc + j][r];
    *(f16x4*)(Tt + (size_t)(n0 + r) * 1024 + k0 + cc) = v;
  }
}

// ---------------- GEMM ----------------
// MODE 0: fused QKV, 128x128 tile. Bt=Wcat[3072][1024]; seg 0->Q, 1->K, 2->V^T.
// MODE 2: out-proj, 128x64 tile (grid 512 = 2 blocks/CU), fp32 + bias.
template <int MODE>
__global__ __launch_bounds__(256, 2)
void gemm_k(const f16* __restrict__ A, const f16* __restrict__ Bt,
            f16* __restrict__ oQ, f16* __restrict__ oK, f16* __restrict__ oV,
            float* __restrict__ oO, const float* __restrict__ bias) {
  constexpr int Kd = 1024;
  constexpr int BN = (MODE == 2) ? 64 : 128;
  constexpr int NF = BN / 32;
  __shared__ f16 smem[128 * 64 + BN * 64];
  f16* sA = smem;
  f16* sB = smem + 128 * 64;
  const int tid = threadIdx.x;
  const int lane = tid & 63, wid = tid >> 6;
  const int wr = wid >> 1, wc = wid & 1;
  const int bm = blockIdx.y * 128, bn = blockIdx.x * BN;

  f32x4 acc[4][NF] = {};

  for (int k0 = 0; k0 < Kd; k0 += 64) {
#pragma unroll
    for (int p = 0; p < 4; ++p) {
      int c = p * 256 + tid;
      int row = c >> 3;
      int gc = (c & 7) ^ (row & 7);
      gload16(A + (size_t)(bm + row) * Kd + k0 + gc * 8, sA + c * 8);
    }
#pragma unroll
    for (int p = 0; p < NF; ++p) {
      int c = p * 256 + tid;
      int row = c >> 3;
      int gc = (c & 7) ^ (row & 7);
      gload16(Bt + (size_t)(bn + row) * Kd + k0 + gc * 8, sB + c * 8);
    }
    __syncthreads();
#pragma unroll
    for (int ks = 0; ks < 2; ++ks) {
      f16x8 af[4], bf[NF];
#pragma unroll
      for (int m = 0; m < 4; ++m) {
        int row = wr * 64 + m * 16 + (lane & 15);
        int j = (ks * 4 + (lane >> 4)) ^ (row & 7);
        af[m] = *(const f16x8*)((const char*)sA + row * 128 + j * 16);
      }
#pragma unroll
      for (int n = 0; n < NF; ++n) {
        int row = wc * (BN / 2) + n * 16 + (lane & 15);
        int j = (ks * 4 + (lane >> 4)) ^ (row & 7);
        bf[n] = *(const f16x8*)((const char*)sB + row * 128 + j * 16);
      }
#pragma unroll
      for (int m = 0; m < 4; ++m)
#pragma unroll
        for (int n = 0; n < NF; ++n)
          acc[m][n] = __builtin_amdgcn_mfma_f32_16x16x32_f16(af[m], bf[n], acc[m][n], 0, 0, 0);
    }
    __syncthreads();
  }

  if constexpr (MODE == 2) {
#pragma unroll
    for (int m = 0; m < 4; ++m) {
      int rbase = bm + wr * 64 + m * 16 + ((lane >> 4) << 2);
#pragma unroll
      for (int n = 0; n < NF; ++n) {
        int ncol = bn + wc * (BN / 2) + n * 16 + (lane & 15);
        float bv = bias[ncol];
#pragma unroll
        for (int i = 0; i < 4; ++i)
          oO[(size_t)(rbase + i) * 1024 + ncol] = acc[m][n][i] + bv;
      }
    }
  } else {
    const int seg = bn >> 10;
    if (seg < 2) {
      f16* dst = seg == 0 ? oQ : oK;
#pragma unroll
      for (int m = 0; m < 4; ++m) {
        int rbase = bm + wr * 64 + m * 16 + ((lane >> 4) << 2);
#pragma unroll
        for (int n = 0; n < NF; ++n) {
          int ncol = (bn & 1023) + wc * 64 + n * 16 + (lane & 15);
          int h = ncol >> 6, dh = ncol & 63;
#pragma unroll
          for (int i = 0; i < 4; ++i) {
            int rr = rbase + i;
            int b = rr >> 11, s = rr & 2047;
            dst[(((size_t)(b * 16 + h) * 2048 + s) << 6) + dh] = (f16)acc[m][n][i];
          }
        }
      }
    } else {
      f16* T64 = smem;                   // [64][132]
      int b = bm >> 11, sbase = bm & 2047;
      int bnl = bn & 1023;
#pragma unroll
      for (int p = 0; p < 2; ++p) {
        if (wr == p) {
#pragma unroll
          for (int m = 0; m < 4; ++m)
#pragma unroll
            for (int n = 0; n < NF; ++n)
#pragma unroll
              for (int i = 0; i < 4; ++i) {
                int rl = m * 16 + ((lane >> 4) << 2) + i;
                int col = wc * 64 + n * 16 + (lane & 15);
                T64[rl * 132 + col] = (f16)acc[m][n][i];
              }
        }
        __syncthreads();
#pragma unroll
        for (int it = 0; it < 4; ++it) {
          int oc = it * 256 + tid;
          int ocol = oc >> 3;
          int och = oc & 7;
          f16x8 v;
#pragma unroll
          for (int j = 0; j < 8; ++j) v[j] = T64[(och * 8 + j) * 132 + ocol];
          int ncol = bnl + ocol;
          int h = ncol >> 6, dh = ncol & 63;
          *(f16x8*)(oV + ((size_t)((b * 16 + h) * 64 + dh) << 11) + sbase + p * 64 + och * 8) = v;
        }
        __syncthreads();
      }
    }
  }
}

// ---------------- causal flash attention ----------------
// grid (16, 32) = 512 blocks, 4 waves; 128-row q-tile per block, each wave
// owns TWO 16-row q-groups (rows qt*128 + wid*32 + g*16). The two groups'
// QK^T->softmax->PV chains are independent -> in-wave MFMA/VALU overlap.
// CU-balance swizzle: ids c & c+256 get qt=bx and 15-bx (34 iters/slot).
// Swapped QK^T (mfma(K,Q) -> S^T): lane-local softmax (R7-verified body).
__global__ __launch_bounds__(256, 2)
void attn_k(const f16* __restrict__ Q, const f16* __restrict__ Kg,
            const f16* __restrict__ Vt, f16* __restrict__ ctx) {
  __shared__ f16 sK[64 * 64];
  __shared__ f16 sV[64 * 64];
  __shared__ f16 sP[4][16 * 64];
  const int tid = threadIdx.x, lane = tid & 63, wid = tid >> 6;
  const int bh = blockIdx.y;
  const int b = bh >> 4, h = bh & 15;
  const int qt = ((bh >> 4) & 1) ? (15 - (int)blockIdx.x) : (int)blockIdx.x;
  const f16* Qb = Q + ((size_t)bh << 17);
  const f16* Kb = Kg + ((size_t)bh << 17);
  const f16* Vb = Vt + ((size_t)bh << 17);
  const float SC = 0.1803368801f;            // 0.125 * log2(e)

  // two 16-row q-groups per wave
  int qbase[2];
  qbase[0] = qt * 128 + wid * 32;
  qbase[1] = qbase[0] + 16;
  f16x8 qf[2][2];
#pragma unroll
  for (int g = 0; g < 2; ++g) {
    const f16* qp = Qb + (size_t)(qbase[g] + (lane & 15)) * 64 + ((lane >> 4) << 3);
    qf[g][0] = *(const f16x8*)(qp);
    qf[g][1] = *(const f16x8*)(qp + 32);
  }

  f32x4 acc[2][4] = {};
  float m_run[2] = {-INFINITY, -INFINITY}, l_run[2] = {0.f, 0.f};
  const int nkt = 2 * qt + 2;                // KV tiles of 64 covering 128 rows

  for (int kt = 0; kt < nkt; ++kt) {
#pragma unroll
    for (int p = 0; p < 2; ++p) {
      int c = p * 256 + tid;
      int row = c >> 3;
      int gc = (c & 7) ^ (row & 7);
      gload16(Kb + (size_t)(kt * 64 + row) * 64 + gc * 8, sK + c * 8);
      gload16(Vb + (size_t)row * 2048 + kt * 64 + gc * 8, sV + c * 8);
    }
    __syncthreads();

    char* Pw = (char*)(sP[wid]);
#pragma unroll
    for (int g = 0; g < 2; ++g) {
      const int qb = qbase[g];
      const int qg = qb + (lane & 15);
      const int qmax_w = qb + 15;
      if (kt * 64 > qmax_w) continue;        // wave-uniform: tile fully masked

      // S^T = K Q^T : mfma(A=K_frag, B=Q_frag). Output: row=k_local, col=q.
      f32x4 sf[4];
#pragma unroll
      for (int kc = 0; kc < 4; ++kc) {
        if (kt * 64 + kc * 16 <= qmax_w) {
          f32x4 z = {};
#pragma unroll
          for (int ks = 0; ks < 2; ++ks) {
            int row = kc * 16 + (lane & 15);
            int j = (ks * 4 + (lane >> 4)) ^ (row & 7);
            f16x8 kf = *(const f16x8*)((const char*)sK + row * 128 + j * 16);
            z = __builtin_amdgcn_mfma_f32_16x16x32_f16(kf, qf[g][ks], z, 0, 0, 0);
          }
          sf[kc] = z;
        } else {
          sf[kc] = (f32x4){-1e30f, -1e30f, -1e30f, -1e30f};
        }
      }
#pragma unroll
      for (int kc = 0; kc < 4; ++kc) {
        if (kt * 64 + kc * 16 + 15 > qb) {
#pragma unroll
          for (int i = 0; i < 4; ++i) {
            int kg = kt * 64 + kc * 16 + ((lane >> 4) << 2) + i;
            sf[kc][i] = (kg <= qg) ? sf[kc][i] * SC : -1e30f;
          }
        } else {
#pragma unroll
          for (int i = 0; i < 4; ++i) sf[kc][i] *= SC;
        }
      }
      float v01 = fmaxf(fmaxf(sf[0][0], sf[0][1]), fmaxf(sf[0][2], sf[0][3]));
      float v23 = fmaxf(fmaxf(sf[1][0], sf[1][1]), fmaxf(sf[1][2], sf[1][3]));
      float v45 = fmaxf(fmaxf(sf[2][0], sf[2][1]), fmaxf(sf[2][2], sf[2][3]));
      float v67 = fmaxf(fmaxf(sf[3][0], sf[3][1]), fmaxf(sf[3][2], sf[3][3]));
      float v = fmaxf(fmaxf(v01, v23), fmaxf(v45, v67));
      v = fmaxf(v, __shfl_xor(v, 16));
      v = fmaxf(v, __shfl_xor(v, 32));
      float mn = fmaxf(m_run[g], v);
      float scl = __builtin_amdgcn_exp2f(m_run[g] - mn);
      m_run[g] = mn;
      float ls = 0.f;
#pragma unroll
      for (int kc = 0; kc < 4; ++kc)
#pragma unroll
        for (int i = 0; i < 4; ++i) {
          float p = __builtin_amdgcn_exp2f(sf[kc][i] - mn);
          sf[kc][i] = p;
          ls += p;
        }
      ls += __shfl_xor(ls, 16);
      ls += __shfl_xor(ls, 32);
      l_run[g] = l_run[g] * scl + ls;
#pragma unroll
      for (int i = 0; i < 4; ++i) {
        float sb = __shfl(scl, ((lane >> 4) << 2) + i);
#pragma unroll
        for (int d = 0; d < 4; ++d) acc[g][d][i] *= sb;
      }
      // P^T -> P[q][k] wave-private LDS (reused per group; DS ops in-order)
#pragma unroll
      for (int kc = 0; kc < 4; ++kc) {
        int kbase = kc * 16 + ((lane >> 4) << 2);
        int ch = kbase >> 3;
        f16x4 pv = { (f16)sf[kc][0], (f16)sf[kc][1], (f16)sf[kc][2], (f16)sf[kc][3] };
        *(f16x4*)(Pw + (lane & 15) * 128 + ((ch ^ (lane & 7)) << 4) + ((kbase & 7) << 1)) = pv;
      }
#pragma unroll
      for (int kk = 0; kk < 2; ++kk) {
        if (kt * 64 + kk * 32 <= qmax_w) {
          int prow = lane & 15;
          int pj = (kk * 4 + (lane >> 4)) ^ (prow & 7);
          f16x8 pa = *(const f16x8*)(Pw + prow * 128 + pj * 16);
#pragma unroll
          for (int d = 0; d < 4; ++d) {
            int vrow = d * 16 + (lane & 15);
            int vj = (kk * 4 + (lane >> 4)) ^ (vrow & 7);
            f16x8 vf = *(const f16x8*)((const char*)sV + vrow * 128 + vj * 16);
            acc[g][d] = __builtin_amdgcn_mfma_f32_16x16x32_f16(pa, vf, acc[g][d], 0, 0, 0);
          }
        }
      }
    }
    __syncthreads();
  }
  // normalize + write ctx f16 [b][s][h*64+d]
#pragma unroll
  for (int g = 0; g < 2; ++g)
#pragma unroll
    for (int i = 0; i < 4; ++i) {
      float lb = __shfl(l_run[g], ((lane >> 4) << 2) + i);
      float r = 1.f / lb;
      int s = qbase[g] + ((lane >> 4) << 2) + i;
#pragma unroll
      for (int d = 0; d < 4; ++d) {
        float val = acc[g][d][i] * r;
        ctx[((size_t)(b * 2048 + s) << 10) + (h << 6) + (d << 4) + (lane & 15)] = (f16)val;
      }
    }
}

extern "C" void kernel_launch(void* const* d_in, const int* in_sizes, int n_in,
                              void* d_out, int out_size, void* d_ws, size_t ws_size,
                              hipStream_t stream) {
  const float* x  = (const float*)d_in[0];
  const float* Wq = (const float*)d_in[1];
  const float* Wk = (const float*)d_in[2];
  const float* Wv = (const float*)d_in[3];
  const float* Wo = (const float*)d_in[4];
  const float* bo = (const float*)d_in[5];
  char* ws = (char*)d_ws;
  f16* xb   = (f16*)(ws);
  f16* Wcat = (f16*)(ws + ((size_t)8  << 20));
  f16* Wot  = (f16*)(ws + ((size_t)14 << 20));
  f16* Qb   = (f16*)(ws + ((size_t)16 << 20));
  f16* Kb   = (f16*)(ws + ((size_t)24 << 20));
  f16* Vtb  = (f16*)(ws + ((size_t)32 << 20));
  f16* ctx  = (f16*)(ws + ((size_t)40 << 20));
  const size_t MM = (size_t)1024 * 1024;

  hipLaunchKernelGGL(cvt_x, dim3(4096), dim3(256), 0, stream, x, xb);
  hipLaunchKernelGGL(cvt_w, dim3(16, 16, 4), dim3(256), 0, stream,
                     Wq, Wk, Wv, Wo, Wcat, Wcat + MM, Wcat + 2 * MM, Wot);
  hipLaunchKernelGGL((gemm_k<0>), dim3(24, 32), dim3(256), 0, stream,
                     xb, Wcat, Qb, Kb, Vtb, nullptr, nullptr);
  hipLaunchKernelGGL(attn_k, dim3(16, 32), dim3(256), 0, stream, Qb, Kb, Vtb, ctx);
  hipLaunchKernelGGL((gemm_k<2>), dim3(16, 32), dim3(256), 0, stream,
                     ctx, Wot, nullptr, nullptr, nullptr, (float*)d_out, bo);
}

// Round 14
// 186.637 us; speedup vs baseline: 1.1383x; 1.1383x over previous
//
#include <hip/hip_runtime.h>

// B=2, S=2048, D=1024, H=16, DH=64. fp32 in/out, f16 MFMA internally.
// ws: xb(8M) Wcat(6M)@8M Wot(2M)@14M Q(8M)@16M K(8M)@24M Vt(8M)@32M ctx(8M)@40M

typedef _Float16 f16;
typedef _Float16 f16x8 __attribute__((ext_vector_type(8)));
typedef _Float16 f16x4 __attribute__((ext_vector_type(4)));
typedef float    f32x4 __attribute__((ext_vector_type(4)));

__device__ __forceinline__ void gload16(const void* g, void* l) {
  __builtin_amdgcn_global_load_lds(
      (const __attribute__((address_space(1))) void*)g,
      (__attribute__((address_space(3))) void*)l, 16, 0, 0);
}

// ---------------- converts ----------------
__global__ void cvt_x(const float* __restrict__ x, f16* __restrict__ xb) {
  int idx = blockIdx.x * 256 + threadIdx.x;
  float4 v = ((const float4*)x)[idx];
  f16x4 o = { (f16)v.x, (f16)v.y, (f16)v.z, (f16)v.w };
  ((f16x4*)xb)[idx] = o;
}

__global__ void cvt_w(const float* __restrict__ W0, const float* __restrict__ W1,
                      const float* __restrict__ W2, const float* __restrict__ W3,
                      f16* __restrict__ T0, f16* __restrict__ T1,
                      f16* __restrict__ T2, f16* __restrict__ T3) {
  const float* W = blockIdx.z == 0 ? W0 : blockIdx.z == 1 ? W1 : blockIdx.z == 2 ? W2 : W3;
  f16*        Tt = blockIdx.z == 0 ? T0 : blockIdx.z == 1 ? T1 : blockIdx.z == 2 ? T2 : T3;
  __shared__ f16 tile[64][65];
  int tid = threadIdx.x;
  int k0 = blockIdx.y * 64, n0 = blockIdx.x * 64;
  int rr = tid >> 4, cc = (tid & 15) * 4;
#pragma unroll
  for (int p = 0; p < 4; ++p) {
    int r = rr + p * 16;
    float4 v = *(const float4*)(W + (size_t)(k0 + r) * 1024 + n0 + cc);
    tile[r][cc + 0] = (f16)v.x; tile[r][cc + 1] = (f16)v.y;
    tile[r][cc + 2] = (f16)v.z; tile[r][cc + 3] = (f16)v.w;
  }
  __syncthreads();
#pragma unroll
  for (int p = 0; p < 4; ++p) {
    int r = rr + p * 16;
    f16x4 v;
#pragma unroll
    for (int j = 0; j < 4; ++j) v[j] = tile[cc + j][r];
    *(f16x4*)(Tt + (size_t)(n0 + r) * 1024 + k0 + cc) = v;
  }
}

// ---------------- GEMM ----------------
// MODE 0: fused QKV, 128x128 tile. Bt=Wcat[3072][1024]; seg 0->Q, 1->K, 2->V^T.
// MODE 2: out-proj, 128x64 tile (grid 512 = 2 blocks/CU), fp32 + bias.
template <int MODE>
__global__ __launch_bounds__(256, 2)
void gemm_k(const f16* __restrict__ A, const f16* __restrict__ Bt,
            f16* __restrict__ oQ, f16* __restrict__ oK, f16* __restrict__ oV,
            float* __restrict__ oO, const float* __restrict__ bias) {
  constexpr int Kd = 1024;
  constexpr int BN = (MODE == 2) ? 64 : 128;
  constexpr int NF = BN / 32;
  __shared__ f16 smem[128 * 64 + BN * 64];
  f16* sA = smem;
  f16* sB = smem + 128 * 64;
  const int tid = threadIdx.x;
  const int lane = tid & 63, wid = tid >> 6;
  const int wr = wid >> 1, wc = wid & 1;
  const int bm = blockIdx.y * 128, bn = blockIdx.x * BN;

  f32x4 acc[4][NF] = {};

  for (int k0 = 0; k0 < Kd; k0 += 64) {
#pragma unroll
    for (int p = 0; p < 4; ++p) {
      int c = p * 256 + tid;
      int row = c >> 3;
      int gc = (c & 7) ^ (row & 7);
      gload16(A + (size_t)(bm + row) * Kd + k0 + gc * 8, sA + c * 8);
    }
#pragma unroll
    for (int p = 0; p < NF; ++p) {
      int c = p * 256 + tid;
      int row = c >> 3;
      int gc = (c & 7) ^ (row & 7);
      gload16(Bt + (size_t)(bn + row) * Kd + k0 + gc * 8, sB + c * 8);
    }
    __syncthreads();
#pragma unroll
    for (int ks = 0; ks < 2; ++ks) {
      f16x8 af[4], bf[NF];
#pragma unroll
      for (int m = 0; m < 4; ++m) {
        int row = wr * 64 + m * 16 + (lane & 15);
        int j = (ks * 4 + (lane >> 4)) ^ (row & 7);
        af[m] = *(const f16x8*)((const char*)sA + row * 128 + j * 16);
      }
#pragma unroll
      for (int n = 0; n < NF; ++n) {
        int row = wc * (BN / 2) + n * 16 + (lane & 15);
        int j = (ks * 4 + (lane >> 4)) ^ (row & 7);
        bf[n] = *(const f16x8*)((const char*)sB + row * 128 + j * 16);
      }
#pragma unroll
      for (int m = 0; m < 4; ++m)
#pragma unroll
        for (int n = 0; n < NF; ++n)
          acc[m][n] = __builtin_amdgcn_mfma_f32_16x16x32_f16(af[m], bf[n], acc[m][n], 0, 0, 0);
    }
    __syncthreads();
  }

  if constexpr (MODE == 2) {
#pragma unroll
    for (int m = 0; m < 4; ++m) {
      int rbase = bm + wr * 64 + m * 16 + ((lane >> 4) << 2);
#pragma unroll
      for (int n = 0; n < NF; ++n) {
        int ncol = bn + wc * (BN / 2) + n * 16 + (lane & 15);
        float bv = bias[ncol];
#pragma unroll
        for (int i = 0; i < 4; ++i)
          oO[(size_t)(rbase + i) * 1024 + ncol] = acc[m][n][i] + bv;
      }
    }
  } else {
    const int seg = bn >> 10;
    if (seg < 2) {
      f16* dst = seg == 0 ? oQ : oK;
#pragma unroll
      for (int m = 0; m < 4; ++m) {
        int rbase = bm + wr * 64 + m * 16 + ((lane >> 4) << 2);
#pragma unroll
        for (int n = 0; n < NF; ++n) {
          int ncol = (bn & 1023) + wc * 64 + n * 16 + (lane & 15);
          int h = ncol >> 6, dh = ncol & 63;
#pragma unroll
          for (int i = 0; i < 4; ++i) {
            int rr = rbase + i;
            int b = rr >> 11, s = rr & 2047;
            dst[(((size_t)(b * 16 + h) * 2048 + s) << 6) + dh] = (f16)acc[m][n][i];
          }
        }
      }
    } else {
      f16* T64 = smem;                   // [64][132]
      int b = bm >> 11, sbase = bm & 2047;
      int bnl = bn & 1023;
#pragma unroll
      for (int p = 0; p < 2; ++p) {
        if (wr == p) {
#pragma unroll
          for (int m = 0; m < 4; ++m)
#pragma unroll
            for (int n = 0; n < NF; ++n)
#pragma unroll
              for (int i = 0; i < 4; ++i) {
                int rl = m * 16 + ((lane >> 4) << 2) + i;
                int col = wc * 64 + n * 16 + (lane & 15);
                T64[rl * 132 + col] = (f16)acc[m][n][i];
              }
        }
        __syncthreads();
#pragma unroll
        for (int it = 0; it < 4; ++it) {
          int oc = it * 256 + tid;
          int ocol = oc >> 3;
          int och = oc & 7;
          f16x8 v;
#pragma unroll
          for (int j = 0; j < 8; ++j) v[j] = T64[(och * 8 + j) * 132 + ocol];
          int ncol = bnl + ocol;
          int h = ncol >> 6, dh = ncol & 63;
          *(f16x8*)(oV + ((size_t)((b * 16 + h) * 64 + dh) << 11) + sbase + p * 64 + och * 8) = v;
        }
        __syncthreads();
      }
    }
  }
}

// ---------------- causal flash attention ----------------
// grid (32, 32) = 1024 blocks (4/CU), 4 waves; ONE 64-row q-tile per block
// (R10-verified residency/swizzle). NEW: stage 128 KV rows per barrier pair,
// run the 64-row compute body twice per stage -> half the barriers/staging
// issues, same FETCH bytes. LDS 40KB = exactly 4 blocks/CU.
__global__ __launch_bounds__(256, 2)
void attn_k(const f16* __restrict__ Q, const f16* __restrict__ Kg,
            const f16* __restrict__ Vt, f16* __restrict__ ctx) {
  __shared__ f16 sK[128 * 64];      // [s 0..127][d], 8 chunks/row, XOR-swizzled
  __shared__ f16 sV[64 * 128];      // [d 0..63][s 0..127], 16 chunks/row, swizzled
  __shared__ f16 sP[4][16 * 64];
  const int tid = threadIdx.x, lane = tid & 63, wid = tid >> 6;
  const int bh = blockIdx.y;
  const int b = bh >> 4, h = bh & 15;
  const int qt = ((bh >> 3) & 1) ? (31 - (int)blockIdx.x) : (int)blockIdx.x;
  const f16* Qb = Q + ((size_t)bh << 17);
  const f16* Kb = Kg + ((size_t)bh << 17);
  const f16* Vb = Vt + ((size_t)bh << 17);
  const float SC = 0.1803368801f;            // 0.125 * log2(e)

  const int qbase = qt * 64 + wid * 16;
  const int qg = qbase + (lane & 15);
  const int qmax_w = qbase + 15;

  f16x8 qf[2];
  {
    const f16* qp = Qb + (size_t)(qbase + (lane & 15)) * 64 + ((lane >> 4) << 3);
    qf[0] = *(const f16x8*)(qp);
    qf[1] = *(const f16x8*)(qp + 32);
  }

  f32x4 acc[4] = {};
  float m_run = -INFINITY, l_run = 0.f;
  const int nkt = (qt >> 1) + 1;             // 128-row KV tiles

  for (int kt = 0; kt < nkt; ++kt) {
    // stage K: 128 rows x 64 d (1024 x 16B chunks)
#pragma unroll
    for (int p = 0; p < 4; ++p) {
      int c = p * 256 + tid;
      int row = c >> 3;                       // 0..127
      int gc = (c & 7) ^ (row & 7);
      gload16(Kb + (size_t)(kt * 128 + row) * 64 + gc * 8, sK + c * 8);
    }
    // stage V^T: 64 d-rows x 128 s (1024 x 16B chunks)
#pragma unroll
    for (int p = 0; p < 4; ++p) {
      int c = p * 256 + tid;
      int drow = c >> 4;                      // 0..63
      int gc = (c & 15) ^ (drow & 7);
      gload16(Vb + (size_t)drow * 2048 + kt * 128 + gc * 8, sV + c * 8);
    }
    __syncthreads();

    char* Pw = (char*)(sP[wid]);
#pragma unroll
    for (int sub = 0; sub < 2; ++sub) {
      const int koff = kt * 128 + sub * 64;
      if (koff > qmax_w) break;               // wave-uniform

      // S^T = K Q^T
      f32x4 sf[4];
#pragma unroll
      for (int kc = 0; kc < 4; ++kc) {
        if (koff + kc * 16 <= qmax_w) {
          f32x4 z = {};
#pragma unroll
          for (int ks = 0; ks < 2; ++ks) {
            int row = sub * 64 + kc * 16 + (lane & 15);
            int j = (ks * 4 + (lane >> 4)) ^ (row & 7);
            f16x8 kf = *(const f16x8*)((const char*)sK + row * 128 + j * 16);
            z = __builtin_amdgcn_mfma_f32_16x16x32_f16(kf, qf[ks], z, 0, 0, 0);
          }
          sf[kc] = z;
        } else {
          sf[kc] = (f32x4){-1e30f, -1e30f, -1e30f, -1e30f};
        }
      }
#pragma unroll
      for (int kc = 0; kc < 4; ++kc) {
        if (koff + kc * 16 + 15 > qbase) {
#pragma unroll
          for (int i = 0; i < 4; ++i) {
            int kg = koff + kc * 16 + ((lane >> 4) << 2) + i;
            sf[kc][i] = (kg <= qg) ? sf[kc][i] * SC : -1e30f;
          }
        } else {
#pragma unroll
          for (int i = 0; i < 4; ++i) sf[kc][i] *= SC;
        }
      }
      // lane-local row softmax (q = lane&15)
      float v01 = fmaxf(fmaxf(sf[0][0], sf[0][1]), fmaxf(sf[0][2], sf[0][3]));
      float v23 = fmaxf(fmaxf(sf[1][0], sf[1][1]), fmaxf(sf[1][2], sf[1][3]));
      float v45 = fmaxf(fmaxf(sf[2][0], sf[2][1]), fmaxf(sf[2][2], sf[2][3]));
      float v67 = fmaxf(fmaxf(sf[3][0], sf[3][1]), fmaxf(sf[3][2], sf[3][3]));
      float v = fmaxf(fmaxf(v01, v23), fmaxf(v45, v67));
      v = fmaxf(v, __shfl_xor(v, 16));
      v = fmaxf(v, __shfl_xor(v, 32));
      float mn = fmaxf(m_run, v);
      float scl = __builtin_amdgcn_exp2f(m_run - mn);
      m_run = mn;
      float ls = 0.f;
#pragma unroll
      for (int kc = 0; kc < 4; ++kc)
#pragma unroll
        for (int i = 0; i < 4; ++i) {
          float p = __builtin_amdgcn_exp2f(sf[kc][i] - mn);
          sf[kc][i] = p;
          ls += p;
        }
      ls += __shfl_xor(ls, 16);
      ls += __shfl_xor(ls, 32);
      l_run = l_run * scl + ls;
#pragma unroll
      for (int i = 0; i < 4; ++i) {
        float sb = __shfl(scl, ((lane >> 4) << 2) + i);
#pragma unroll
        for (int d = 0; d < 4; ++d) acc[d][i] *= sb;
      }
      // P^T -> P[q][k] wave-private LDS
#pragma unroll
      for (int kc = 0; kc < 4; ++kc) {
        int kbase = kc * 16 + ((lane >> 4) << 2);
        int ch = kbase >> 3;
        f16x4 pv = { (f16)sf[kc][0], (f16)sf[kc][1], (f16)sf[kc][2], (f16)sf[kc][3] };
        *(f16x4*)(Pw + (lane & 15) * 128 + ((ch ^ (lane & 7)) << 4) + ((kbase & 7) << 1)) = pv;
      }
      // ctx += P V
#pragma unroll
      for (int kk = 0; kk < 2; ++kk) {
        if (koff + kk * 32 <= qmax_w) {
          int prow = lane & 15;
          int pj = (kk * 4 + (lane >> 4)) ^ (prow & 7);
          f16x8 pa = *(const f16x8*)(Pw + prow * 128 + pj * 16);
#pragma unroll
          for (int d = 0; d < 4; ++d) {
            int vrow = d * 16 + (lane & 15);                 // LDS d-row 0..63
            int vch = (sub * 8 + kk * 4 + (lane >> 4)) ^ (vrow & 7);
            f16x8 vf = *(const f16x8*)((const char*)sV + vrow * 256 + vch * 16);
            acc[d] = __builtin_amdgcn_mfma_f32_16x16x32_f16(pa, vf, acc[d], 0, 0, 0);
          }
        }
      }
    }
    __syncthreads();
  }
  // normalize + write ctx f16 [b][s][h*64+d]
#pragma unroll
  for (int i = 0; i < 4; ++i) {
    float lb = __shfl(l_run, ((lane >> 4) << 2) + i);
    float r = 1.f / lb;
    int s = qbase + ((lane >> 4) << 2) + i;
#pragma unroll
    for (int d = 0; d < 4; ++d) {
      float val = acc[d][i] * r;
      ctx[((size_t)(b * 2048 + s) << 10) + (h << 6) + (d << 4) + (lane & 15)] = (f16)val;
    }
  }
}

extern "C" void kernel_launch(void* const* d_in, const int* in_sizes, int n_in,
                              void* d_out, int out_size, void* d_ws, size_t ws_size,
                              hipStream_t stream) {
  const float* x  = (const float*)d_in[0];
  const float* Wq = (const float*)d_in[1];
  const float* Wk = (const float*)d_in[2];
  const float* Wv = (const float*)d_in[3];
  const float* Wo = (const float*)d_in[4];
  const float* bo = (const float*)d_in[5];
  char* ws = (char*)d_ws;
  f16* xb   = (f16*)(ws);
  f16* Wcat = (f16*)(ws + ((size_t)8  << 20));
  f16* Wot  = (f16*)(ws + ((size_t)14 << 20));
  f16* Qb   = (f16*)(ws + ((size_t)16 << 20));
  f16* Kb   = (f16*)(ws + ((size_t)24 << 20));
  f16* Vtb  = (f16*)(ws + ((size_t)32 << 20));
  f16* ctx  = (f16*)(ws + ((size_t)40 << 20));
  const size_t MM = (size_t)1024 * 1024;

  hipLaunchKernelGGL(cvt_x, dim3(4096), dim3(256), 0, stream, x, xb);
  hipLaunchKernelGGL(cvt_w, dim3(16, 16, 4), dim3(256), 0, stream,
                     Wq, Wk, Wv, Wo, Wcat, Wcat + MM, Wcat + 2 * MM, Wot);
  hipLaunchKernelGGL((gemm_k<0>), dim3(24, 32), dim3(256), 0, stream,
                     xb, Wcat, Qb, Kb, Vtb, nullptr, nullptr);
  hipLaunchKernelGGL(attn_k, dim3(32, 32), dim3(256), 0, stream, Qb, Kb, Vtb, ctx);
  hipLaunchKernelGGL((gemm_k<2>), dim3(16, 32), dim3(256), 0, stream,
                     ctx, Wot, nullptr, nullptr, nullptr, (float*)d_out, bo);
}

// Round 15
// 181.065 us; speedup vs baseline: 1.1733x; 1.0308x over previous
//
#include <hip/hip_runtime.h>

// B=2, S=2048, D=1024, H=16, DH=64. fp32 in/out, f16 MFMA internally.
// ws: xb(8M) Wcat(6M)@8M Wot(2M)@14M Q(8M)@16M K(8M)@24M Vt(8M)@32M ctx(8M)@40M

typedef _Float16 f16;
typedef _Float16 f16x8 __attribute__((ext_vector_type(8)));
typedef _Float16 f16x4 __attribute__((ext_vector_type(4)));
typedef float    f32x4 __attribute__((ext_vector_type(4)));

__device__ __forceinline__ void gload16(const void* g, void* l) {
  __builtin_amdgcn_global_load_lds(
      (const __attribute__((address_space(1))) void*)g,
      (__attribute__((address_space(3))) void*)l, 16, 0, 0);
}

// ---------------- converts ----------------
__global__ void cvt_x(const float* __restrict__ x, f16* __restrict__ xb) {
  int idx = blockIdx.x * 256 + threadIdx.x;
  float4 v = ((const float4*)x)[idx];
  f16x4 o = { (f16)v.x, (f16)v.y, (f16)v.z, (f16)v.w };
  ((f16x4*)xb)[idx] = o;
}

__global__ void cvt_w(const float* __restrict__ W0, const float* __restrict__ W1,
                      const float* __restrict__ W2, const float* __restrict__ W3,
                      f16* __restrict__ T0, f16* __restrict__ T1,
                      f16* __restrict__ T2, f16* __restrict__ T3) {
  const float* W = blockIdx.z == 0 ? W0 : blockIdx.z == 1 ? W1 : blockIdx.z == 2 ? W2 : W3;
  f16*        Tt = blockIdx.z == 0 ? T0 : blockIdx.z == 1 ? T1 : blockIdx.z == 2 ? T2 : T3;
  __shared__ f16 tile[64][65];
  int tid = threadIdx.x;
  int k0 = blockIdx.y * 64, n0 = blockIdx.x * 64;
  int rr = tid >> 4, cc = (tid & 15) * 4;
#pragma unroll
  for (int p = 0; p < 4; ++p) {
    int r = rr + p * 16;
    float4 v = *(const float4*)(W + (size_t)(k0 + r) * 1024 + n0 + cc);
    tile[r][cc + 0] = (f16)v.x; tile[r][cc + 1] = (f16)v.y;
    tile[r][cc + 2] = (f16)v.z; tile[r][cc + 3] = (f16)v.w;
  }
  __syncthreads();
#pragma unroll
  for (int p = 0; p < 4; ++p) {
    int r = rr + p * 16;
    f16x4 v;
#pragma unroll
    for (int j = 0; j < 4; ++j) v[j] = tile[cc + j][r];
    *(f16x4*)(Tt + (size_t)(n0 + r) * 1024 + k0 + cc) = v;
  }
}

// ---------------- GEMM ----------------
// MODE 0: fused QKV, 128x128 tile. Bt=Wcat[3072][1024]; seg 0->Q, 1->K, 2->V^T.
// MODE 2: out-proj, 128x64 tile (grid 512 = 2 blocks/CU), fp32 + bias.
template <int MODE>
__global__ __launch_bounds__(256, 2)
void gemm_k(const f16* __restrict__ A, const f16* __restrict__ Bt,
            f16* __restrict__ oQ, f16* __restrict__ oK, f16* __restrict__ oV,
            float* __restrict__ oO, const float* __restrict__ bias) {
  constexpr int Kd = 1024;
  constexpr int BN = (MODE == 2) ? 64 : 128;
  constexpr int NF = BN / 32;
  __shared__ f16 smem[128 * 64 + BN * 64];
  f16* sA = smem;
  f16* sB = smem + 128 * 64;
  const int tid = threadIdx.x;
  const int lane = tid & 63, wid = tid >> 6;
  const int wr = wid >> 1, wc = wid & 1;
  const int bm = blockIdx.y * 128, bn = blockIdx.x * BN;

  f32x4 acc[4][NF] = {};

  for (int k0 = 0; k0 < Kd; k0 += 64) {
#pragma unroll
    for (int p = 0; p < 4; ++p) {
      int c = p * 256 + tid;
      int row = c >> 3;
      int gc = (c & 7) ^ (row & 7);
      gload16(A + (size_t)(bm + row) * Kd + k0 + gc * 8, sA + c * 8);
    }
#pragma unroll
    for (int p = 0; p < NF; ++p) {
      int c = p * 256 + tid;
      int row = c >> 3;
      int gc = (c & 7) ^ (row & 7);
      gload16(Bt + (size_t)(bn + row) * Kd + k0 + gc * 8, sB + c * 8);
    }
    __syncthreads();
#pragma unroll
    for (int ks = 0; ks < 2; ++ks) {
      f16x8 af[4], bf[NF];
#pragma unroll
      for (int m = 0; m < 4; ++m) {
        int row = wr * 64 + m * 16 + (lane & 15);
        int j = (ks * 4 + (lane >> 4)) ^ (row & 7);
        af[m] = *(const f16x8*)((const char*)sA + row * 128 + j * 16);
      }
#pragma unroll
      for (int n = 0; n < NF; ++n) {
        int row = wc * (BN / 2) + n * 16 + (lane & 15);
        int j = (ks * 4 + (lane >> 4)) ^ (row & 7);
        bf[n] = *(const f16x8*)((const char*)sB + row * 128 + j * 16);
      }
#pragma unroll
      for (int m = 0; m < 4; ++m)
#pragma unroll
        for (int n = 0; n < NF; ++n)
          acc[m][n] = __builtin_amdgcn_mfma_f32_16x16x32_f16(af[m], bf[n], acc[m][n], 0, 0, 0);
    }
    __syncthreads();
  }

  if constexpr (MODE == 2) {
#pragma unroll
    for (int m = 0; m < 4; ++m) {
      int rbase = bm + wr * 64 + m * 16 + ((lane >> 4) << 2);
#pragma unroll
      for (int n = 0; n < NF; ++n) {
        int ncol = bn + wc * (BN / 2) + n * 16 + (lane & 15);
        float bv = bias[ncol];
#pragma unroll
        for (int i = 0; i < 4; ++i)
          oO[(size_t)(rbase + i) * 1024 + ncol] = acc[m][n][i] + bv;
      }
    }
  } else {
    const int seg = bn >> 10;
    if (seg < 2) {
      f16* dst = seg == 0 ? oQ : oK;
#pragma unroll
      for (int m = 0; m < 4; ++m) {
        int rbase = bm + wr * 64 + m * 16 + ((lane >> 4) << 2);
#pragma unroll
        for (int n = 0; n < NF; ++n) {
          int ncol = (bn & 1023) + wc * 64 + n * 16 + (lane & 15);
          int h = ncol >> 6, dh = ncol & 63;
#pragma unroll
          for (int i = 0; i < 4; ++i) {
            int rr = rbase + i;
            int b = rr >> 11, s = rr & 2047;
            dst[(((size_t)(b * 16 + h) * 2048 + s) << 6) + dh] = (f16)acc[m][n][i];
          }
        }
      }
    } else {
      f16* T64 = smem;                   // [64][132]
      int b = bm >> 11, sbase = bm & 2047;
      int bnl = bn & 1023;
#pragma unroll
      for (int p = 0; p < 2; ++p) {
        if (wr == p) {
#pragma unroll
          for (int m = 0; m < 4; ++m)
#pragma unroll
            for (int n = 0; n < NF; ++n)
#pragma unroll
              for (int i = 0; i < 4; ++i) {
                int rl = m * 16 + ((lane >> 4) << 2) + i;
                int col = wc * 64 + n * 16 + (lane & 15);
                T64[rl * 132 + col] = (f16)acc[m][n][i];
              }
        }
        __syncthreads();
#pragma unroll
        for (int it = 0; it < 4; ++it) {
          int oc = it * 256 + tid;
          int ocol = oc >> 3;
          int och = oc & 7;
          f16x8 v;
#pragma unroll
          for (int j = 0; j < 8; ++j) v[j] = T64[(och * 8 + j) * 132 + ocol];
          int ncol = bnl + ocol;
          int h = ncol >> 6, dh = ncol & 63;
          *(f16x8*)(oV + ((size_t)((b * 16 + h) * 64 + dh) << 11) + sbase + p * 64 + och * 8) = v;
        }
        __syncthreads();
      }
    }
  }
}

// ---------------- causal flash attention ----------------
// grid (32, 32) = 1024 blocks (4/CU), 4 waves; ONE 64-row q-tile per block,
// 128 KV rows staged per barrier pair (R14-verified). NEW this round:
//  (a) l via ones-MFMA -> lacc f32x4 in acc row-layout (kills serial sum
//      reduce + epilogue shfl),
//  (b) T13 defer-max THR=8 (skip rescale while __all(v <= m+8); P <= 2^8),
//  (c) softmax scale folded into Q at load (no per-iter scale muls).
__global__ __launch_bounds__(256, 2)
void attn_k(const f16* __restrict__ Q, const f16* __restrict__ Kg,
            const f16* __restrict__ Vt, f16* __restrict__ ctx) {
  __shared__ f16 sK[128 * 64];
  __shared__ f16 sV[64 * 128];
  __shared__ f16 sP[4][16 * 64];
  const int tid = threadIdx.x, lane = tid & 63, wid = tid >> 6;
  const int bh = blockIdx.y;
  const int b = bh >> 4, h = bh & 15;
  const int qt = ((bh >> 3) & 1) ? (31 - (int)blockIdx.x) : (int)blockIdx.x;
  const f16* Qb = Q + ((size_t)bh << 17);
  const f16* Kb = Kg + ((size_t)bh << 17);
  const f16* Vb = Vt + ((size_t)bh << 17);
  const float SC = 0.1803368801f;            // 0.125 * log2(e)

  const int qbase = qt * 64 + wid * 16;
  const int qg = qbase + (lane & 15);
  const int qmax_w = qbase + 15;

  // Q fragments, pre-scaled by SC (folds softmax scale into QK^T)
  f16x8 qf[2];
  {
    const f16* qp = Qb + (size_t)(qbase + (lane & 15)) * 64 + ((lane >> 4) << 3);
    f16x8 r0 = *(const f16x8*)(qp);
    f16x8 r1 = *(const f16x8*)(qp + 32);
#pragma unroll
    for (int j = 0; j < 8; ++j) {
      qf[0][j] = (f16)((float)r0[j] * SC);
      qf[1][j] = (f16)((float)r1[j] * SC);
    }
  }

  const f16x8 ones = { (f16)1, (f16)1, (f16)1, (f16)1, (f16)1, (f16)1, (f16)1, (f16)1 };
  f32x4 acc[4] = {};
  f32x4 lacc = {};                            // row-sums of P, acc row-layout
  float m_run = -INFINITY;
  const int nkt = (qt >> 1) + 1;              // 128-row KV tiles

  for (int kt = 0; kt < nkt; ++kt) {
#pragma unroll
    for (int p = 0; p < 4; ++p) {
      int c = p * 256 + tid;
      int row = c >> 3;
      int gc = (c & 7) ^ (row & 7);
      gload16(Kb + (size_t)(kt * 128 + row) * 64 + gc * 8, sK + c * 8);
    }
#pragma unroll
    for (int p = 0; p < 4; ++p) {
      int c = p * 256 + tid;
      int drow = c >> 4;
      int gc = (c & 15) ^ (drow & 7);
      gload16(Vb + (size_t)drow * 2048 + kt * 128 + gc * 8, sV + c * 8);
    }
    __syncthreads();

    char* Pw = (char*)(sP[wid]);
#pragma unroll
    for (int sub = 0; sub < 2; ++sub) {
      const int koff = kt * 128 + sub * 64;
      if (koff > qmax_w) break;

      // S^T = K Q^T (pre-scaled)
      f32x4 sf[4];
#pragma unroll
      for (int kc = 0; kc < 4; ++kc) {
        if (koff + kc * 16 <= qmax_w) {
          f32x4 z = {};
#pragma unroll
          for (int ks = 0; ks < 2; ++ks) {
            int row = sub * 64 + kc * 16 + (lane & 15);
            int j = (ks * 4 + (lane >> 4)) ^ (row & 7);
            f16x8 kf = *(const f16x8*)((const char*)sK + row * 128 + j * 16);
            z = __builtin_amdgcn_mfma_f32_16x16x32_f16(kf, qf[ks], z, 0, 0, 0);
          }
          sf[kc] = z;
        } else {
          sf[kc] = (f32x4){-1e30f, -1e30f, -1e30f, -1e30f};
        }
      }
      // causal mask (diagonal-crossing kc tiles only; no scale mul needed)
#pragma unroll
      for (int kc = 0; kc < 4; ++kc) {
        if (koff + kc * 16 + 15 > qbase) {
#pragma unroll
          for (int i = 0; i < 4; ++i) {
            int kg = koff + kc * 16 + ((lane >> 4) << 2) + i;
            if (kg > qg) sf[kc][i] = -1e30f;
          }
        }
      }
      // row max (q = lane&15 lane-local) + defer-max
      float v01 = fmaxf(fmaxf(sf[0][0], sf[0][1]), fmaxf(sf[0][2], sf[0][3]));
      float v23 = fmaxf(fmaxf(sf[1][0], sf[1][1]), fmaxf(sf[1][2], sf[1][3]));
      float v45 = fmaxf(fmaxf(sf[2][0], sf[2][1]), fmaxf(sf[2][2], sf[2][3]));
      float v67 = fmaxf(fmaxf(sf[3][0], sf[3][1]), fmaxf(sf[3][2], sf[3][3]));
      float v = fmaxf(fmaxf(v01, v23), fmaxf(v45, v67));
      v = fmaxf(v, __shfl_xor(v, 16));
      v = fmaxf(v, __shfl_xor(v, 32));
      if (!__all(v <= m_run + 8.f)) {         // rescale only when max grew >THR
        float mn = fmaxf(m_run, v);
        float scl = __builtin_amdgcn_exp2f(m_run - mn);
        m_run = mn;
#pragma unroll
        for (int i = 0; i < 4; ++i) {
          float sb = __shfl(scl, ((lane >> 4) << 2) + i);
#pragma unroll
          for (int d = 0; d < 4; ++d) acc[d][i] *= sb;
          lacc[i] *= sb;
        }
      }
      // P = exp2(S - m); pack to wave-private LDS
#pragma unroll
      for (int kc = 0; kc < 4; ++kc) {
        int kbase = kc * 16 + ((lane >> 4) << 2);
        int ch = kbase >> 3;
        f16x4 pv;
#pragma unroll
        for (int i = 0; i < 4; ++i)
          pv[i] = (f16)__builtin_amdgcn_exp2f(sf[kc][i] - m_run);
        *(f16x4*)(Pw + (lane & 15) * 128 + ((ch ^ (lane & 7)) << 4) + ((kbase & 7) << 1)) = pv;
      }
      // ctx += P V ; l += P * 1 (ones-MFMA, same acc row-layout)
#pragma unroll
      for (int kk = 0; kk < 2; ++kk) {
        if (koff + kk * 32 <= qmax_w) {
          int prow = lane & 15;
          int pj = (kk * 4 + (lane >> 4)) ^ (prow & 7);
          f16x8 pa = *(const f16x8*)(Pw + prow * 128 + pj * 16);
          lacc = __builtin_amdgcn_mfma_f32_16x16x32_f16(pa, ones, lacc, 0, 0, 0);
#pragma unroll
          for (int d = 0; d < 4; ++d) {
            int vrow = d * 16 + (lane & 15);
            int vch = (sub * 8 + kk * 4 + (lane >> 4)) ^ (vrow & 7);
            f16x8 vf = *(const f16x8*)((const char*)sV + vrow * 256 + vch * 16);
            acc[d] = __builtin_amdgcn_mfma_f32_16x16x32_f16(pa, vf, acc[d], 0, 0, 0);
          }
        }
      }
    }
    __syncthreads();
  }
  // normalize (lacc already in acc row-layout: no shfl) + write ctx
#pragma unroll
  for (int i = 0; i < 4; ++i) {
    float r = 1.f / lacc[i];
    int s = qbase + ((lane >> 4) << 2) + i;
#pragma unroll
    for (int d = 0; d < 4; ++d) {
      float val = acc[d][i] * r;
      ctx[((size_t)(b * 2048 + s) << 10) + (h << 6) + (d << 4) + (lane & 15)] = (f16)val;
    }
  }
}

extern "C" void kernel_launch(void* const* d_in, const int* in_sizes, int n_in,
                              void* d_out, int out_size, void* d_ws, size_t ws_size,
                              hipStream_t stream) {
  const float* x  = (const float*)d_in[0];
  const float* Wq = (const float*)d_in[1];
  const float* Wk = (const float*)d_in[2];
  const float* Wv = (const float*)d_in[3];
  const float* Wo = (const float*)d_in[4];
  const float* bo = (const float*)d_in[5];
  char* ws = (char*)d_ws;
  f16* xb   = (f16*)(ws);
  f16* Wcat = (f16*)(ws + ((size_t)8  << 20));
  f16* Wot  = (f16*)(ws + ((size_t)14 << 20));
  f16* Qb   = (f16*)(ws + ((size_t)16 << 20));
  f16* Kb   = (f16*)(ws + ((size_t)24 << 20));
  f16* Vtb  = (f16*)(ws + ((size_t)32 << 20));
  f16* ctx  = (f16*)(ws + ((size_t)40 << 20));
  const size_t MM = (size_t)1024 * 1024;

  hipLaunchKernelGGL(cvt_x, dim3(4096), dim3(256), 0, stream, x, xb);
  hipLaunchKernelGGL(cvt_w, dim3(16, 16, 4), dim3(256), 0, stream,
                     Wq, Wk, Wv, Wo, Wcat, Wcat + MM, Wcat + 2 * MM, Wot);
  hipLaunchKernelGGL((gemm_k<0>), dim3(24, 32), dim3(256), 0, stream,
                     xb, Wcat, Qb, Kb, Vtb, nullptr, nullptr);
  hipLaunchKernelGGL(attn_k, dim3(32, 32), dim3(256), 0, stream, Qb, Kb, Vtb, ctx);
  hipLaunchKernelGGL((gemm_k<2>), dim3(16, 32), dim3(256), 0, stream,
                     ctx, Wot, nullptr, nullptr, nullptr, (float*)d_out, bo);
}